// Round 10
// baseline (3176.169 us; speedup 1.0000x reference)
//
#include <hip/hip_runtime.h>
#include <hip/hip_bf16.h>

#define SLEN 128
#define BAT 64
#define EDIM 512
#define HDIM 1024
#define VOC 10000
#define VPAD 10112     // 79 * 128
#define NWG_REC 144
#define TPB_REC 512

typedef short v8s __attribute__((ext_vector_type(8)));
typedef float v4f __attribute__((ext_vector_type(4)));
typedef unsigned short u16;

__device__ __forceinline__ u16 f2bf(float f) {
  unsigned u = __float_as_uint(f);
  u += 0x7fffu + ((u >> 16) & 1u);   // RNE
  return (u16)(u >> 16);
}
__device__ __forceinline__ float bf2f(u16 b) {
  return __uint_as_float(((unsigned)b) << 16);
}
__device__ __forceinline__ float sigm(float x) { return 1.f / (1.f + __expf(-x)); }
__device__ __forceinline__ float tanh_f(float x) { return 1.f - 2.f / (1.f + __expf(2.f * x)); }

// ---- LLC-point scalar state accessors (relaxed agent atomics, no fences) ---------
__device__ __forceinline__ void st_f32(float* p, float v) {
  __hip_atomic_store(p, v, __ATOMIC_RELAXED, __HIP_MEMORY_SCOPE_AGENT);
}
__device__ __forceinline__ float ld_f32(const float* p) {
  return __hip_atomic_load(p, __ATOMIC_RELAXED, __HIP_MEMORY_SCOPE_AGENT);
}
__device__ __forceinline__ float ld_bf16(const unsigned* base, int elem) {
  unsigned pr = __hip_atomic_load(base + (elem >> 1), __ATOMIC_RELAXED, __HIP_MEMORY_SCOPE_AGENT);
  return bf2f((u16)((elem & 1) ? (pr >> 16) : (pr & 0xffffu)));
}
// bf16 pair store: lanes l (even) and l^1 hold adjacent elements; even lane stores u32
__device__ __forceinline__ void st_bf16_pair(unsigned* base, int elem, u16 val, int l) {
  unsigned p = (unsigned)__shfl_xor((int)val, 1);
  if ((l & 1) == 0)
    __hip_atomic_store(base + (elem >> 1), (unsigned)val | (p << 16),
                       __ATOMIC_RELAXED, __HIP_MEMORY_SCOPE_AGENT);
}

#define POLL(COND)                                   \
  do {                                               \
    if (t < 64) {                                    \
      for (;;) {                                     \
        bool ok_ = (COND);                           \
        if (__all(ok_)) break;                       \
        __builtin_amdgcn_s_sleep(1);                 \
      }                                              \
    }                                                \
    __syncthreads();                                 \
  } while (0)

#define FENCE_FLAG(FIDX)                                                        \
  do {                                                                          \
    asm volatile("s_waitcnt vmcnt(0) lgkmcnt(0)" ::: "memory");                 \
    __syncthreads();                                                            \
    if (t == 0)                                                                 \
      __hip_atomic_store(&bar[FIDX], T + 1, __ATOMIC_RELAXED,                   \
                         __HIP_MEMORY_SCOPE_AGENT);                             \
  } while (0)

// ---- cooperative LDS-staged 64x(64cols)x1024 GEMM, depth-5 ring ------------------
// All 8 waves pull A (64x1024 bf16, row stride 2KB) through a 2x8KB LDS double
// buffer (16 chunks of 64 k-elems; 1 dwordx4/thread/chunk; 5 chunks in flight).
// Each wave: rg=w>>1 rows, cg=w&1 col-half; computes TWO 16-col fragments.
__device__ __forceinline__ void gemm64(const char* Asrc, char* stage,
                                       const char* bb, int swz,
                                       int t, int rg, int lr, int lk2,
                                       v4f& acc0, v4f& acc1) {
  const char* gp = Asrc + (t >> 3) * 2048 + (t & 7) * 16;
  char* wp = stage + (t >> 3) * 128 + (((t & 7) * 16) ^ (((t >> 3) & 7) << 4));
  const char* rp = stage + (rg * 16 + lr) * 128;
  v8s sreg[5];
#pragma unroll
  for (int j = 0; j < 5; ++j)
    asm volatile("global_load_dwordx4 %0, %1, off offset:%2 sc0 sc1"
                 : "=v"(sreg[j]) : "v"(gp), "i"(j * 128));
  asm volatile("s_waitcnt vmcnt(4)" ::: "memory");
  __builtin_amdgcn_sched_barrier(0);
  *(v8s*)wp = sreg[0];
  __syncthreads();
#pragma unroll
  for (int c = 0; c < 16; ++c) {
    if (c < 11)
      asm volatile("global_load_dwordx4 %0, %1, off offset:%2 sc0 sc1"
                   : "=v"(sreg[c % 5]) : "v"(gp), "i"((c + 5) * 128));
    if (c < 15) {
      asm volatile("s_waitcnt vmcnt(%0)" :: "i"((c < 11) ? 4 : (14 - c)));
      __builtin_amdgcn_sched_barrier(0);
      *(v8s*)(wp + ((c + 1) & 1) * 8192) = sreg[(c + 1) % 5];
    }
    const char* buf = rp + (c & 1) * 8192;
#pragma unroll
    for (int ls = 0; ls < 2; ++ls) {
      v8s a = *(const v8s*)(buf + ((ls * 64 + lk2) ^ swz));
      v8s b0v = *(const v8s*)(bb + (((c * 2 + ls) * 64 + lk2) ^ swz));
      v8s b1v = *(const v8s*)(bb + 32768 + (((c * 2 + ls) * 64 + lk2) ^ swz));
      acc0 = __builtin_amdgcn_mfma_f32_16x16x32_bf16(a, b0v, acc0, 0, 0, 0);
      acc1 = __builtin_amdgcn_mfma_f32_16x16x32_bf16(a, b1v, acc1, 0, 0, 0);
    }
    __syncthreads();
  }
}

// ---------------- persistent 2-layer GRU recurrence (5 disjoint groups) -----------
// 144 WGs x 512 thr, 64 weight-cols/WG (128KB) + 16KB stage = 144KB LDS.
// Groups (one staged gemm per tick each):
//  A wg[0,32):    rz0(T)    T<128        flags bar[0..31]
//  B wg[32,48):   ht0(T)    T<128        flags bar[32..47]
//  C wg[48,96):   xp1(T-1)  1<=T<=128    flags bar[48..95]
//  D wg[96,128):  rz1(T-2)  2<=T<=129    flags bar[96..127]
//  E wg[128,144): ht1(T-2)  2<=T<=129    flags bar[128..143]
// State parity-double-buffered (state s in buf[s&1]). Waits (flag=iter+1):
//  A: fB>=T | B: fA>=T+1, post fC>=T | C: fB>=T, post fD>=T && fE>=T
//  D: fE>=T, post fC>=T | E: fD>=T+1 (fC>=T transitively via D)
// Critical chain per tick: A -> B. Layer-1 track C->D->E runs in parallel.
__global__ void __launch_bounds__(TPB_REC, 2) k_recur(
    const u16* __restrict__ Uh0b, const u16* __restrict__ Wx1b, const u16* __restrict__ Uh1b,
    const float* __restrict__ b0, const float* __restrict__ b1,
    const u16* __restrict__ xa0,
    float* __restrict__ h0f, u16* __restrict__ h0b,
    float* __restrict__ h1f, u16* __restrict__ h1b,
    u16* __restrict__ a2, float* __restrict__ z0,
    u16* __restrict__ a5, float* __restrict__ z1,
    u16* __restrict__ xp1,
    u16* __restrict__ hs1,
    float* __restrict__ outh,
    int* __restrict__ bar) {
  extern __shared__ char smem[];
  const int wg = blockIdx.x;
  const int t = threadIdx.x;
  const int w = t >> 6;
  const int l = t & 63;
  const int lr = l & 15;
  const int lk2 = (l >> 4) * 16;
  const int rg = w >> 1, cg = w & 1;
  const int rbase = rg * 16 + ((l >> 4) << 2);
  const int swz = (lr & 7) << 4;
  char* stage = smem + 131072;

  unsigned* a2u  = (unsigned*)a2;
  unsigned* a5u  = (unsigned*)a5;
  unsigned* h0bu = (unsigned*)h0b;
  unsigned* h1bu = (unsigned*)h1b;
  unsigned* xpu  = (unsigned*)xp1;

  auto lf = [&](int i) {
    return __hip_atomic_load(&bar[i], __ATOMIC_RELAXED, __HIP_MEMORY_SCOPE_AGENT);
  };

  // ---- one-time weight staging into swizzled LDS (64 cols) ----
  {
    const u16* wsrc; int wrow0;
    if (wg < 32)       { wsrc = Uh0b; wrow0 = wg * 64; }            // rz0
    else if (wg < 48)  { wsrc = Uh0b; wrow0 = 2048 + (wg - 32) * 64; }  // ht0
    else if (wg < 96)  { wsrc = Wx1b; wrow0 = (wg - 48) * 64; }     // xp1
    else if (wg < 128) { wsrc = Uh1b; wrow0 = (wg - 96) * 64; }     // rz1
    else               { wsrc = Uh1b; wrow0 = 2048 + (wg - 128) * 64; } // ht1
    for (int i = t; i < 8192; i += TPB_REC) {          // 64 cols * 128 x 16B
      int c = i >> 7, j = i & 127;
      v8s v = *(const v8s*)(wsrc + (size_t)(wrow0 + c) * HDIM + j * 8);
      *(v8s*)(smem + c * 2048 + ((j * 16) ^ ((c & 7) << 4))) = v;
    }
    __syncthreads();
  }

  const char* bb = smem + (cg * 32 + lr) * 2048;   // fragment 0 col base; frag1 +32KB

  if (wg < 32) {
    // ============== A: rz0(T) -> a2[T&1], z0[T&1] ==============
    const int g = wg >> 4;
    const int o0 = ((wg * 64) & 1023) + cg * 32 + lr;
    const float biasA0 = b0[g * HDIM + o0];
    const float biasA1 = b0[g * HDIM + o0 + 16];
    for (int T = 0; T <= SLEN + 1; ++T) {
      if (T < SLEN) {
        if (T >= 1) POLL(lf(32 + (t & 15)) >= T);          // fB
        const int pr = (T - 1) & 1, pw = T & 1;
        float xv[2][4], hv[2][4];
#pragma unroll
        for (int f = 0; f < 2; ++f) {
          const int o = o0 + f * 16;
#pragma unroll
          for (int r = 0; r < 4; ++r) {
            int b = rbase + r;
            xv[f][r] = bf2f(xa0[((T * 3 + g) * BAT + b) * HDIM + o]);
            if (g == 0) hv[f][r] = ld_f32(h0f + pr * 65536 + b * HDIM + o);
          }
        }
        v4f acc0{0.f,0.f,0.f,0.f}, acc1{0.f,0.f,0.f,0.f};
        gemm64((const char*)(h0b + pr * 65536), stage, bb, swz, t, rg, lr, lk2, acc0, acc1);
#pragma unroll
        for (int f = 0; f < 2; ++f) {
          const int o = o0 + f * 16;
          const float bias = f ? biasA1 : biasA0;
          v4f& acc = f ? acc1 : acc0;
#pragma unroll
          for (int r = 0; r < 4; ++r) {
            int b = rbase + r;
            float s = sigm(acc[r] + xv[f][r] + bias);
            if (g == 0) st_bf16_pair(a2u + pw * 32768, b * HDIM + o, f2bf(s * hv[f][r]), l);
            else        st_f32(z0 + pw * 65536 + b * HDIM + o, s);
          }
        }
      }
      FENCE_FLAG(wg);
    }
  } else if (wg < 48) {
    // ============== B: ht0(T) -> h0 state T ==============
    const int j = wg - 32;
    const int o0 = j * 64 + cg * 32 + lr;
    const float biasB0 = b0[2 * HDIM + o0];
    const float biasB1 = b0[2 * HDIM + o0 + 16];
    for (int T = 0; T <= SLEN + 1; ++T) {
      if (T < SLEN) {
        POLL(lf(t & 31) >= T + 1);                         // fA (a2,z0 ready)
        const int pr = (T - 1) & 1, pw = T & 1;
        float xv[2][4], hv[2][4], zv[2][4];
#pragma unroll
        for (int f = 0; f < 2; ++f) {
          const int o = o0 + f * 16;
#pragma unroll
          for (int r = 0; r < 4; ++r) {
            int b = rbase + r;
            xv[f][r] = bf2f(xa0[((T * 3 + 2) * BAT + b) * HDIM + o]);
            hv[f][r] = ld_f32(h0f + pr * 65536 + b * HDIM + o);
            zv[f][r] = ld_f32(z0 + pw * 65536 + b * HDIM + o);
          }
        }
        v4f acc0{0.f,0.f,0.f,0.f}, acc1{0.f,0.f,0.f,0.f};
        gemm64((const char*)(a2 + pw * 65536), stage, bb, swz, t, rg, lr, lk2, acc0, acc1);
        POLL(t < 48 ? lf(48 + t) >= T : true);             // fC (WAR on h0b[pw])
#pragma unroll
        for (int f = 0; f < 2; ++f) {
          const int o = o0 + f * 16;
          const float bias = f ? biasB1 : biasB0;
          v4f& acc = f ? acc1 : acc0;
#pragma unroll
          for (int r = 0; r < 4; ++r) {
            int b = rbase + r;
            float ht = tanh_f(xv[f][r] + acc[r] + bias);
            float hn = (1.f - zv[f][r]) * hv[f][r] + zv[f][r] * ht;
            st_f32(h0f + pw * 65536 + b * HDIM + o, hn);
            st_bf16_pair(h0bu + pw * 32768, b * HDIM + o, f2bf(hn), l);
            if (T == SLEN - 1) outh[b * HDIM + o] = hn;
          }
        }
      }
      FENCE_FLAG(32 + j);
    }
  } else if (wg < 96) {
    // ============== C: xp1(T-1) ==============
    const int j = wg - 48;
    const int n0 = j * 64 + cg * 32 + lr;
    for (int T = 0; T <= SLEN + 1; ++T) {
      if (T >= 1 && T <= SLEN) {
        POLL(lf(32 + (t & 15)) >= T);                      // fB (h0 state T-1)
        const int ps = (T - 1) & 1;
        v4f acc0{0.f,0.f,0.f,0.f}, acc1{0.f,0.f,0.f,0.f};
        gemm64((const char*)(h0b + ps * 65536), stage, bb, swz, t, rg, lr, lk2, acc0, acc1);
        POLL(lf(96 + (t & 31)) >= T && lf(128 + (t & 15)) >= T);  // fD,fE (WAR on xp1)
        unsigned* xp = xpu + ps * 98304;
#pragma unroll
        for (int f = 0; f < 2; ++f) {
          const int n = n0 + f * 16;
          v4f& acc = f ? acc1 : acc0;
#pragma unroll
          for (int r = 0; r < 4; ++r)
            st_bf16_pair(xp, (rbase + r) * 3072 + n, f2bf(acc[r]), l);
        }
      }
      FENCE_FLAG(48 + j);
    }
  } else if (wg < 128) {
    // ============== D: rz1(T-2) -> a5, z1 ==============
    const int j = wg - 96;
    const int g = j >> 4;
    const int o0 = ((j * 64) & 1023) + cg * 32 + lr;
    const float biasD0 = b1[g * HDIM + o0];
    const float biasD1 = b1[g * HDIM + o0 + 16];
    for (int T = 0; T <= SLEN + 1; ++T) {
      if (T >= 2) {
        POLL(lf(128 + (t & 15)) >= T);                     // fE (h1 state T-3)
        const int s = T - 2, ps = s & 1, pm = (T - 1) & 1;
        float hv[2][4];
        if (g == 0)
#pragma unroll
          for (int f = 0; f < 2; ++f)
#pragma unroll
            for (int r = 0; r < 4; ++r)
              hv[f][r] = ld_f32(h1f + pm * 65536 + (rbase + r) * HDIM + o0 + f * 16);
        v4f acc0{0.f,0.f,0.f,0.f}, acc1{0.f,0.f,0.f,0.f};
        gemm64((const char*)(h1b + pm * 65536), stage, bb, swz, t, rg, lr, lk2, acc0, acc1);
        POLL(t < 48 ? lf(48 + t) >= T : true);             // fC (xp1 state s)
#pragma unroll
        for (int f = 0; f < 2; ++f) {
          const int o = o0 + f * 16;
          const float bias = f ? biasD1 : biasD0;
          v4f& acc = f ? acc1 : acc0;
#pragma unroll
          for (int r = 0; r < 4; ++r) {
            int b = rbase + r;
            float pv = ld_bf16(xpu + ps * 98304, b * 3072 + g * HDIM + o);
            float sg = sigm(acc[r] + pv + bias);
            if (g == 0) st_bf16_pair(a5u + ps * 32768, b * HDIM + o, f2bf(sg * hv[f][r]), l);
            else        st_f32(z1 + ps * 65536 + b * HDIM + o, sg);
          }
        }
      }
      FENCE_FLAG(96 + j);
    }
  } else {
    // ============== E: ht1(T-2) -> h1 state T-2, hs1 ==============
    const int j = wg - 128;
    const int o0 = j * 64 + cg * 32 + lr;
    const float biasE0 = b1[2 * HDIM + o0];
    const float biasE1 = b1[2 * HDIM + o0 + 16];
    for (int T = 0; T <= SLEN + 1; ++T) {
      if (T >= 2) {
        POLL(lf(96 + (t & 31)) >= T + 1);                  // fD (a5,z1 ready; fC implied)
        const int s = T - 2, ps = s & 1, pm = (T - 1) & 1;
        float pv[2][4], zv[2][4], hv[2][4];
#pragma unroll
        for (int f = 0; f < 2; ++f) {
          const int o = o0 + f * 16;
#pragma unroll
          for (int r = 0; r < 4; ++r) {
            int b = rbase + r;
            pv[f][r] = ld_bf16(xpu + ps * 98304, b * 3072 + 2048 + o);
            zv[f][r] = ld_f32(z1 + ps * 65536 + b * HDIM + o);
            hv[f][r] = ld_f32(h1f + pm * 65536 + b * HDIM + o);
          }
        }
        v4f acc0{0.f,0.f,0.f,0.f}, acc1{0.f,0.f,0.f,0.f};
        gemm64((const char*)(a5 + ps * 65536), stage, bb, swz, t, rg, lr, lk2, acc0, acc1);
#pragma unroll
        for (int f = 0; f < 2; ++f) {
          const int o = o0 + f * 16;
          const float bias = f ? biasE1 : biasE0;
          v4f& acc = f ? acc1 : acc0;
#pragma unroll
          for (int r = 0; r < 4; ++r) {
            int b = rbase + r;
            float ht = tanh_f(pv[f][r] + acc[r] + bias);
            float hn = (1.f - zv[f][r]) * hv[f][r] + zv[f][r] * ht;
            u16 hb = f2bf(hn);
            st_f32(h1f + ps * 65536 + b * HDIM + o, hn);
            st_bf16_pair(h1bu + ps * 32768, b * HDIM + o, hb, l);
            hs1[((size_t)s * BAT + b) * HDIM + o] = hb;    // normal store
            if (s == SLEN - 1) outh[(size_t)BAT * HDIM + b * HDIM + o] = hn;
          }
        }
      }
      FENCE_FLAG(128 + j);
    }
  }
}

// ---------------- m97-style 128x128 bf16 GEMM ------------------------------------
// MODE 0: xa0 = gather(emb)[8192,512] x Wx0[3072,512]^T -> bf16 out in (S,3,B,H) layout
// MODE 1: logits = hs1[8192,1024] x Wd[VPAD,1024]^T + bd -> f32 (8192,10000)
template <int MODE>
__global__ void __launch_bounds__(256) k_gemm(
    const u16* __restrict__ A, const u16* __restrict__ Bw,
    const int* __restrict__ gidx, const float* __restrict__ bias,
    void* __restrict__ Out) {
  constexpr int K = MODE ? 1024 : 512;
  constexpr int NB_N = MODE ? (VPAD / 128) : (3072 / 128);

  __shared__ u16 sA[128 * 64];
  __shared__ u16 sB[128 * 64];

  const int nwg = gridDim.x;
  const int cpx = nwg >> 3;
  const int bid = blockIdx.x;
  const int swz = (bid & 7) * cpx + (bid >> 3);
  const int bm = swz / NB_N, bn = swz % NB_N;
  const int m0 = bm * 128, n0 = bn * 128;

  const int t = threadIdx.x;
  const int w = t >> 6, l = t & 63;
  const int lr = l & 15, lk = (l >> 4) * 8;
  const int wm = (w >> 1) * 64, wn = (w & 1) * 64;
  const int kc = (t & 7) * 8;

  int arowg[4];
#pragma unroll
  for (int i = 0; i < 4; ++i) {
    int row = m0 + i * 32 + (t >> 3);
    arowg[i] = (MODE == 0) ? gidx[row] : row;
  }
  int brow[4];
#pragma unroll
  for (int i = 0; i < 4; ++i) brow[i] = n0 + i * 32 + (t >> 3);

  v4f acc[4][4];
#pragma unroll
  for (int mi = 0; mi < 4; ++mi)
#pragma unroll
    for (int ni = 0; ni < 4; ++ni) acc[mi][ni] = v4f{0.f, 0.f, 0.f, 0.f};

  for (int k0 = 0; k0 < K; k0 += 64) {
    __syncthreads();
#pragma unroll
    for (int i = 0; i < 4; ++i) {
      const u16* src = A + (size_t)arowg[i] * K + k0 + kc;
      __builtin_amdgcn_global_load_lds((const __attribute__((address_space(1))) void*)src,
                                       (__attribute__((address_space(3))) void*)(sA + i * 2048 + w * 512),
                                       16, 0, 0);
    }
#pragma unroll
    for (int i = 0; i < 4; ++i) {
      const u16* src = Bw + (size_t)brow[i] * K + k0 + kc;
      __builtin_amdgcn_global_load_lds((const __attribute__((address_space(1))) void*)src,
                                       (__attribute__((address_space(3))) void*)(sB + i * 2048 + w * 512),
                                       16, 0, 0);
    }
    asm volatile("s_waitcnt vmcnt(0)" ::: "memory");
    __syncthreads();
#pragma unroll
    for (int ks = 0; ks < 2; ++ks) {
      v8s af[4], bfr[4];
#pragma unroll
      for (int mi = 0; mi < 4; ++mi) af[mi] = *(const v8s*)&sA[(wm + mi * 16 + lr) * 64 + ks * 32 + lk];
#pragma unroll
      for (int ni = 0; ni < 4; ++ni) bfr[ni] = *(const v8s*)&sB[(wn + ni * 16 + lr) * 64 + ks * 32 + lk];
#pragma unroll
      for (int mi = 0; mi < 4; ++mi)
#pragma unroll
        for (int ni = 0; ni < 4; ++ni)
          acc[mi][ni] = __builtin_amdgcn_mfma_f32_16x16x32_bf16(af[mi], bfr[ni], acc[mi][ni], 0, 0, 0);
    }
  }

#pragma unroll
  for (int mi = 0; mi < 4; ++mi)
#pragma unroll
    for (int ni = 0; ni < 4; ++ni)
#pragma unroll
      for (int r = 0; r < 4; ++r) {
        int grow = m0 + wm + mi * 16 + ((l >> 4) << 2) + r;
        int gcol = n0 + wn + ni * 16 + lr;
        float v = acc[mi][ni][r];
        if (MODE == 0) {
          int s = grow >> 6, b = grow & 63;
          int g = gcol >> 10, o = gcol & 1023;
          ((u16*)Out)[(((size_t)s * 3 + g) * BAT + b) * HDIM + o] = f2bf(v);
        } else {
          if (gcol < VOC) ((float*)Out)[(size_t)grow * VOC + gcol] = v + bias[gcol];
        }
      }
}

// ---------------- small helper kernels --------------------------------------------
__global__ void k_cvt(const float* __restrict__ src, u16* __restrict__ dst, int n, int nsrc) {
  int i = (blockIdx.x * 256 + threadIdx.x) * 4;
  if (i >= n) return;
#pragma unroll
  for (int j = 0; j < 4; ++j) {
    int idx = i + j;
    if (idx < n) dst[idx] = (idx < nsrc) ? f2bf(src[idx]) : (u16)0;
  }
}

// initial state -> parity-1 buffers (first read is buf[(-1)&1] = buf[1])
__global__ void k_init(const float* __restrict__ hidden,
                       float* h0f, u16* h0b, float* h1f, u16* h1b, int* bar) {
  int i = blockIdx.x * 256 + threadIdx.x;
  if (i < BAT * HDIM) {
    float v0 = hidden[i];
    float v1 = hidden[BAT * HDIM + i];
    h0f[65536 + i] = v0; h0b[65536 + i] = f2bf(v0);
    h1f[65536 + i] = v1; h1b[65536 + i] = f2bf(v1);
  }
  if (i < 512) bar[i] = 0;
}

// ---------------- launcher ---------------------------------------------------------
extern "C" void kernel_launch(void* const* d_in, const int* in_sizes, int n_in,
                              void* d_out, int out_size, void* d_ws, size_t ws_size,
                              hipStream_t stream) {
  const int*   inp = (const int*)d_in[0];
  const float* hid = (const float*)d_in[1];
  const float* emb = (const float*)d_in[2];
  const float* Wx0 = (const float*)d_in[3];
  const float* Uh0 = (const float*)d_in[4];
  const float* b0  = (const float*)d_in[5];
  const float* Wx1 = (const float*)d_in[6];
  const float* Uh1 = (const float*)d_in[7];
  const float* b1  = (const float*)d_in[8];
  const float* Wd  = (const float*)d_in[9];
  const float* bd  = (const float*)d_in[10];

  char* ws = (char*)d_ws;
  size_t off = 0;
  auto alloc = [&](size_t bytes) {
    void* p = ws + off;
    off = (off + bytes + 255) & ~(size_t)255;
    return p;
  };
  u16* emb_b = (u16*)alloc(sizeof(u16) * (size_t)VOC * EDIM);
  u16* Wx0_b = (u16*)alloc(sizeof(u16) * 3 * HDIM * EDIM);
  u16* Uh0_b = (u16*)alloc(sizeof(u16) * 3 * HDIM * HDIM);
  u16* Wx1_b = (u16*)alloc(sizeof(u16) * 3 * HDIM * HDIM);
  u16* Uh1_b = (u16*)alloc(sizeof(u16) * 3 * HDIM * HDIM);
  u16* Wd_b  = (u16*)alloc(sizeof(u16) * (size_t)VPAD * HDIM);
  u16* xa0_b = (u16*)alloc(sizeof(u16) * (size_t)SLEN * 3 * BAT * HDIM);
  u16* hs1_b = (u16*)alloc(sizeof(u16) * (size_t)SLEN * BAT * HDIM);
  u16* xp1   = (u16*)alloc(sizeof(u16) * 2 * BAT * 3 * HDIM);
  float* h0f = (float*)alloc(sizeof(float) * 2 * BAT * HDIM);
  float* h1f = (float*)alloc(sizeof(float) * 2 * BAT * HDIM);
  u16* h0b   = (u16*)alloc(sizeof(u16) * 2 * BAT * HDIM);
  u16* h1b   = (u16*)alloc(sizeof(u16) * 2 * BAT * HDIM);
  u16* a2    = (u16*)alloc(sizeof(u16) * 2 * BAT * HDIM);
  u16* a5    = (u16*)alloc(sizeof(u16) * 2 * BAT * HDIM);
  float* z0  = (float*)alloc(sizeof(float) * 2 * BAT * HDIM);
  float* z1  = (float*)alloc(sizeof(float) * 2 * BAT * HDIM);
  int* bar   = (int*)alloc(sizeof(int) * 512);

  float* logits = (float*)d_out;
  float* outh = logits + (size_t)SLEN * BAT * VOC;

  auto cvt = [&](const float* s, u16* d, int n, int nsrc) {
    k_cvt<<<dim3((n / 4 + 255) / 256), dim3(256), 0, stream>>>(s, d, n, nsrc);
  };
  cvt(emb, emb_b, VOC * EDIM, VOC * EDIM);
  cvt(Wx0, Wx0_b, 3 * HDIM * EDIM, 3 * HDIM * EDIM);
  cvt(Uh0, Uh0_b, 3 * HDIM * HDIM, 3 * HDIM * HDIM);
  cvt(Wx1, Wx1_b, 3 * HDIM * HDIM, 3 * HDIM * HDIM);
  cvt(Uh1, Uh1_b, 3 * HDIM * HDIM, 3 * HDIM * HDIM);
  cvt(Wd, Wd_b, VPAD * HDIM, VOC * HDIM);
  k_init<<<dim3(256), dim3(256), 0, stream>>>(hid, h0f, h0b, h1f, h1b, bar);

  k_gemm<0><<<dim3(64 * 24), dim3(256), 0, stream>>>(emb_b, Wx0_b, inp, (const float*)nullptr, (void*)xa0_b);

  (void)hipFuncSetAttribute(reinterpret_cast<const void*>(k_recur),
                            hipFuncAttributeMaxDynamicSharedMemorySize, 147456);
  k_recur<<<dim3(NWG_REC), dim3(TPB_REC), 147456, stream>>>(
      Uh0_b, Wx1_b, Uh1_b, b0, b1, xa0_b,
      h0f, h0b, h1f, h1b, a2, z0, a5, z1, xp1, hs1_b, outh, bar);

  k_gemm<1><<<dim3(64 * 79), dim3(256), 0, stream>>>(hs1_b, Wd_b, (const int*)nullptr, bd, d_out);
}